// Round 1
// baseline (172.319 us; speedup 1.0000x reference)
//
#include <hip/hip_runtime.h>
#include <cstdint>

// Problem dims (fixed by the reference)
#define B_DIM 16
#define T_DIM 1024
#define DK    512     // D_IN
#define H_DIM 1024

// Tiling
#define TCH    128                 // t-rows per block (chunk)
#define NCH    (T_DIM / TCH)       // 8 chunks per (b,strip)
#define NB     64                  // output cols per block
#define NSTRIP (H_DIM / NB)        // 16 strips
#define NKQ    (DK / 8)            // 64 16B-chunks along K

typedef __bf16 bf16x8 __attribute__((ext_vector_type(8)));
typedef __bf16 bf16x4 __attribute__((ext_vector_type(4)));
typedef float  f32x4  __attribute__((ext_vector_type(4)));

// ---- async global->LDS (16B per lane, wave-uniform LDS base + lane*16) ----
typedef __attribute__((address_space(1))) unsigned int* as1p;
typedef __attribute__((address_space(3))) unsigned int* as3p;

__device__ __forceinline__ void async_cp16(const void* g, void* l) {
  __builtin_amdgcn_global_load_lds((as1p)(uint64_t)g,
                                   (as3p)(uint32_t)(uint64_t)l, 16, 0, 0);
}

// ---- merged prep: x cvt, W cvt+transpose (k-major 16B chunks), meta, flag zero ----
// grid = 8192 (x) + 512 (W) + 4 (meta) + 512 (flags) = 9220 blocks x 256 thr
__global__ __launch_bounds__(256) void prep(const float* __restrict__ x,
                                            __bf16* __restrict__ xb,
                                            const float* __restrict__ W,
                                            __bf16* __restrict__ wbT,   // [NKQ][H][8]
                                            const float* __restrict__ raw_a,
                                            float4* __restrict__ meta,
                                            unsigned long long* __restrict__ flags) {
  const int bid = blockIdx.x, tid = threadIdx.x;
  if (bid < 8192) {                       // x: [B*T*DK] f32 -> bf16, 4/thread
    const int i = bid * 256 + tid;        // i < 2097152
    f32x4 v = ((const f32x4*)x)[i];
    bf16x4 o;
    o.x = (__bf16)v.x; o.y = (__bf16)v.y; o.z = (__bf16)v.z; o.w = (__bf16)v.w;
    ((bf16x4*)xb)[i] = o;
  } else if (bid < 8704) {                // W: [H][DK] f32 -> wbT[kq][h][8] bf16
    const int i = (bid - 8192) * 256 + tid;   // i < 131072
    const int h  = i >> 7;                // DK/4 = 128 x4-chunks per row
    const int k0 = (i & 127) * 4;
    f32x4 v = ((const f32x4*)W)[i];
    bf16x4 o;
    o.x = (__bf16)v.x; o.y = (__bf16)v.y; o.z = (__bf16)v.z; o.w = (__bf16)v.w;
    *(bf16x4*)(wbT + ((size_t)(k0 >> 3) * H_DIM + h) * 8 + (k0 & 7)) = o;
  } else if (bid < 8708) {                // meta: {a, log2|a|, neg?, zero?}
    const int h = (bid - 8704) * 256 + tid;
    const float a = tanhf(raw_a[h]);
    const float la2 = log2f(fabsf(a));
    meta[h] = make_float4(a, la2, (a < 0.f) ? 1.f : 0.f, (fabsf(a) < 1e-6f) ? 1.f : 0.f);
  } else {                                // lookback flags: zero 131072 u64
    const int i = (bid - 8708) * 256 + tid;
    flags[i] = 0ULL;
  }
}

// ---- fused: GEMM (z = x W^T + b) + chunk-parallel weighted-cumsum scan ----
// Grid: 2048 blocks = (b,chunk) group g = bid&127 (b = g>>3, chunk = g&7),
// strip = bid>>7.  bid%8 == chunk -> each chunk's x-slice (16b x 128t x 1KB
// = 2MB) + W (1MB) is XCD-L2-resident.  Lookback predecessors of a block are
// strictly lower bid (same b,strip, smaller chunk) -> dispatch-order safe.
// Block: 512 thr / 8 waves: wave = (rw = w&3 row-group of 32 t, cg = w>>2
// col-group of 32 h).  A fragments load straight global->VGPR (no LDS reuse
// exists for A); only the 64-col W panel lives in LDS (staged once, k-major).
__global__ __launch_bounds__(512, 4) void fused_rnn(
    const __bf16* __restrict__ xb,   // [B*T, DK]
    const __bf16* __restrict__ wbT,  // [NKQ][H][8]
    const float* __restrict__ bias,  // [H]
    const float4* __restrict__ meta, // [H]
    const float* __restrict__ h0g,   // [B, H]
    unsigned long long* __restrict__ flags, // [B][NSTRIP][NCH][NB] packed {flag|val}
    float* __restrict__ out) {       // [B*T, H]
  __shared__ __align__(16) __bf16 Bs[NKQ][NB][8];   // 64 KB, Bs[kq][col] = W[col][kq*8..+8]
  __shared__ float chunkTot[4][NB];
  __shared__ float colCarry[NB];

  const int tid  = threadIdx.x;
  const int wave = tid >> 6;
  const int lane = tid & 63;
  const int q  = lane >> 4;      // 0..3
  const int c  = lane & 15;      // 0..15
  const int rw = wave & 3;       // row-wave: rows rw*32..+32
  const int cg = wave >> 2;      // col-group: cols cg*32..+32

  const int bid   = blockIdx.x;
  const int g     = bid & 127;
  const int strip = bid >> 7;    // 0..15
  const int b     = g >> 3;
  const int chunk = g & 7;
  const int t0    = chunk * TCH;
  const int n0    = strip * NB;

  // stage W panel once: 4096 16B chunks / 512 thr = 8 per thread, LDS-linear
#pragma unroll
  for (int it = 0; it < 8; ++it) {
    const int idx = it * 512 + tid;
    const int col = idx & 63, kq = idx >> 6;
    async_cp16(wbT + ((size_t)kq * H_DIM + (n0 + col)) * 8, &Bs[kq][col][0]);
  }

  // per-lane column constants (2 cols per lane: cg*32 + j*16 + c)
  float bias_j[2], la2_j[2], h0_j[2];
  bool neg_j[2], zm_j[2];
#pragma unroll
  for (int j = 0; j < 2; ++j) {
    const int col = n0 + cg * 32 + j * 16 + c;
    bias_j[j] = bias[col];
    const float4 mt = meta[col];
    la2_j[j] = mt.y;
    neg_j[j] = mt.z != 0.f;
    zm_j[j]  = mt.w != 0.f;
    h0_j[j]  = h0g[(size_t)b * H_DIM + col];
  }

  // A row base for this lane: row = t0 + rw*32 + i*16 + c, frag = 16B at k*32+q*8
  const __bf16* const arow =
      xb + ((size_t)(b * T_DIM + t0 + rw * 32 + c)) * DK + q * 8;

  f32x4 acc[2][2];
#pragma unroll
  for (int i = 0; i < 2; ++i)
#pragma unroll
    for (int j = 0; j < 2; ++j) acc[i][j] = (f32x4){0.f, 0.f, 0.f, 0.f};

  __syncthreads();   // Bs staged (drains the 8 cp16s)

  // barrier-free GEMM main loop: 16 ksteps of BK=32
#pragma unroll 4
  for (int k = 0; k < 16; ++k) {
    bf16x8 af[2], bfr[2];
#pragma unroll
    for (int i = 0; i < 2; ++i)
      af[i] = *(const bf16x8*)(arow + (size_t)i * 16 * DK + k * 32);
#pragma unroll
    for (int j = 0; j < 2; ++j)
      bfr[j] = *(const bf16x8*)(&Bs[k * 4 + q][cg * 32 + j * 16 + c][0]);
#pragma unroll
    for (int i = 0; i < 2; ++i)
#pragma unroll
      for (int j = 0; j < 2; ++j)
        acc[i][j] = __builtin_amdgcn_mfma_f32_16x16x32_bf16(af[i], bfr[j], acc[i][j], 0, 0, 0);
  }

  // ---- scan phase 1: per-wave weighted prefix over this wave's 32 rows ----
  // acc[i][j][r] = z for t = t0 + rw*32 + i*16 + q*4 + r, col = n0+cg*32+j*16+c
  f32x4 vloc[2][2];
  float icarry[2] = {0.f, 0.f};
#pragma unroll
  for (int i = 0; i < 2; ++i) {
#pragma unroll
    for (int j = 0; j < 2; ++j) {
      const float la2 = la2_j[j];
      f32x4 w;
#pragma unroll
      for (int r = 0; r < 4; ++r) {
        const int tp1 = t0 + rw * 32 + i * 16 + q * 4 + r + 1;
        const float z = acc[i][j][r] + bias_j[j];
        float inv = fminf(__builtin_amdgcn_exp2f(-la2 * (float)tp1), 1e12f);
        if (neg_j[j] && (tp1 & 1)) inv = 1e12f;   // matches ref's max(p,1e-12) for p<0
        w[r] = z * inv;
      }
      const float pr0 = w[0];
      const float pr1 = pr0 + w[1];
      const float pr2 = pr1 + w[2];
      const float pr3 = pr2 + w[3];
      const float x1 = __shfl_xor(pr3, 16, 64);   // q^1
      const float x2 = __shfl_xor(pr3, 32, 64);   // q^2
      const float x3 = __shfl_xor(pr3, 48, 64);   // q^3
      float sq = 0.f;
      if (q >= 2) sq += x2 + x3;
      if (q & 1) sq += x1;
      const float base = icarry[j] + sq;
      vloc[i][j] = (f32x4){base + pr0, base + pr1, base + pr2, base + pr3};
      icarry[j] += pr3 + x1 + x2 + x3;   // total over this i-group's 16 rows
    }
  }
  if (q == 0) {
#pragma unroll
    for (int j = 0; j < 2; ++j) chunkTot[rw][cg * 32 + j * 16 + c] = icarry[j];
  }
  __syncthreads();

  // ---- publish own chunk total, then decoupled lookback for the carry ----
  if (tid < 64) {
    const int col = tid;
    const size_t fb = ((size_t)b * NSTRIP + strip) * NCH * NB;
    const float tot =
        chunkTot[0][col] + chunkTot[1][col] + chunkTot[2][col] + chunkTot[3][col];
    atomicExch(&flags[fb + (size_t)chunk * NB + col],
               (1ULL << 32) | (unsigned long long)__float_as_uint(tot));
    float s = 0.f;
    for (int p = 0; p < chunk; ++p) {
      unsigned long long v = atomicAdd(&flags[fb + (size_t)p * NB + col], 0ULL);
      while (!(v >> 32)) {
        __builtin_amdgcn_s_sleep(4);
        v = atomicAdd(&flags[fb + (size_t)p * NB + col], 0ULL);
      }
      s += __uint_as_float((unsigned int)v);
    }
    colCarry[col] = s;
  }
  __syncthreads();

  // ---- phase 2: add carry, produce h, write out ----
  float cc[2];
#pragma unroll
  for (int j = 0; j < 2; ++j) {
    const int colL = cg * 32 + j * 16 + c;
    float s = colCarry[colL];
#pragma unroll
    for (int w2 = 0; w2 < 3; ++w2)
      if (w2 < rw) s += chunkTot[w2][colL];
    cc[j] = s;
  }
#pragma unroll
  for (int i = 0; i < 2; ++i) {
#pragma unroll
    for (int j = 0; j < 2; ++j) {
      const float la2 = la2_j[j];
      const int col = n0 + cg * 32 + j * 16 + c;
#pragma unroll
      for (int r = 0; r < 4; ++r) {
        const int tl = t0 + rw * 32 + i * 16 + q * 4 + r;
        const int tp1 = tl + 1;
        float pv = __builtin_amdgcn_exp2f(la2 * (float)tp1);
        if (neg_j[j] && (tp1 & 1)) pv = -pv;
        const float v = cc[j] + vloc[i][j][r];
        const float hv = pv * v + pv * h0_j[j];
        const float zval = acc[i][j][r] + bias_j[j];
        out[(size_t)(b * T_DIM + tl) * H_DIM + col] = zm_j[j] ? zval : hv;
      }
    }
  }
}

extern "C" void kernel_launch(void* const* d_in, const int* in_sizes, int n_in,
                              void* d_out, int out_size, void* d_ws, size_t ws_size,
                              hipStream_t stream) {
  const float* x     = (const float*)d_in[0];  // [B,T,DK]
  const float* h0    = (const float*)d_in[1];  // [B,H]
  const float* raw_a = (const float*)d_in[2];  // [H]
  const float* W     = (const float*)d_in[3];  // [H,DK]
  const float* bias  = (const float*)d_in[4];  // [H]
  float* out = (float*)d_out;                  // [B,T,H]

  char* ws = (char*)d_ws;
  __bf16* xb  = (__bf16*)(ws);                               // 16777216 B
  __bf16* wbT = (__bf16*)(ws + 16777216);                    //  1048576 B
  float4* meta = (float4*)(ws + 16777216 + 1048576);         //    16384 B
  unsigned long long* flags =
      (unsigned long long*)(ws + 16777216 + 1048576 + 16384); // 1048576 B

  prep<<<9220, 256, 0, stream>>>(x, xb, W, wbT, raw_a, meta, flags);
  fused_rnn<<<2048, 512, 0, stream>>>(xb, wbT, bias, meta, h0, flags, out);
}

// Round 2
// 135.186 us; speedup vs baseline: 1.2747x; 1.2747x over previous
//
#include <hip/hip_runtime.h>
#include <cstdint>

// Problem dims (fixed by the reference)
#define B_DIM 16
#define T_DIM 1024
#define DK    512     // D_IN
#define H_DIM 1024

// Tiling
#define TCH    128                 // t-rows per block (chunk)
#define NCH    (T_DIM / TCH)       // 8 chunks per (b,strip)
#define NB     64                  // output cols per block
#define NSTRIP (H_DIM / NB)        // 16 strips
#define NKT    16                  // k-tiles of BK=32
#define BKQ    4                   // 16B k-chunks per k-tile

typedef __bf16 bf16x8 __attribute__((ext_vector_type(8)));
typedef __bf16 bf16x4 __attribute__((ext_vector_type(4)));
typedef float  f32x4  __attribute__((ext_vector_type(4)));

// ---- async global->LDS (16B per lane, wave-uniform LDS base + lane*16) ----
typedef __attribute__((address_space(1))) unsigned int* as1p;
typedef __attribute__((address_space(3))) unsigned int* as3p;

__device__ __forceinline__ void async_cp16(const void* g, void* l) {
  __builtin_amdgcn_global_load_lds((as1p)(uint64_t)g,
                                   (as3p)(uint32_t)(uint64_t)l, 16, 0, 0);
}

// ---- merged prep ----
// x: f32 [B][T][DK] -> bf16 k-major xbt[b][kq=0..63][t=0..1023][8]
//    (so fused staging of a [kq][row] LDS tile is global-coalesced + LDS-linear)
// W: f32 [H][DK]    -> bf16 k-major wbT[kq][h][8]
// meta: {a, log2|a|, neg?, zero?} per h;  flags: zeroed lookback array.
// grid = 4096 (x) + 512 (W) + 4 (meta) + 512 (flags) = 5124 blocks x 256 thr
__global__ __launch_bounds__(256) void prep(const float* __restrict__ x,
                                            __bf16* __restrict__ xbt,
                                            const float* __restrict__ W,
                                            __bf16* __restrict__ wbT,
                                            const float* __restrict__ raw_a,
                                            float4* __restrict__ meta,
                                            unsigned long long* __restrict__ flags) {
  const int bid = blockIdx.x, tid = threadIdx.x;
  if (bid < 4096) {                       // x transpose + cvt, 8 elems/thread
    const int g = bid * 256 + tid;        // < 1048576
    const int b = g >> 16;
    const int r = g & 65535;
    // lane mapping: 4 lanes share a 128B x-row segment (coalesced reads);
    // 16 lanes of one kq write 256B contiguous in xbt (coalesced writes).
    const int kq = ((r >> 12) << 2) | (tid & 3);         // 0..63
    const int t  = (((r >> 6) & 63) << 4) | ((tid & 63) >> 2);  // 0..1023
    const float* src = x + ((size_t)(b * T_DIM + t) * DK + kq * 8);
    f32x4 v0 = ((const f32x4*)src)[0];
    f32x4 v1 = ((const f32x4*)src)[1];
    bf16x8 o;
    o[0] = (__bf16)v0.x; o[1] = (__bf16)v0.y; o[2] = (__bf16)v0.z; o[3] = (__bf16)v0.w;
    o[4] = (__bf16)v1.x; o[5] = (__bf16)v1.y; o[6] = (__bf16)v1.z; o[7] = (__bf16)v1.w;
    *(bf16x8*)(xbt + ((size_t)(b * 64 + kq) * T_DIM + t) * 8) = o;
  } else if (bid < 4608) {                // W -> wbT[kq][h][8]
    const int i = (bid - 4096) * 256 + tid;   // i < 131072
    const int h  = i >> 7;                // DK/4 = 128 x4-chunks per row
    const int k0 = (i & 127) * 4;
    f32x4 v = ((const f32x4*)W)[i];
    bf16x4 o;
    o.x = (__bf16)v.x; o.y = (__bf16)v.y; o.z = (__bf16)v.z; o.w = (__bf16)v.w;
    *(bf16x4*)(wbT + ((size_t)(k0 >> 3) * H_DIM + h) * 8 + (k0 & 7)) = o;
  } else if (bid < 4612) {                // meta
    const int h = (bid - 4608) * 256 + tid;
    const float a = tanhf(raw_a[h]);
    const float la2 = log2f(fabsf(a));
    meta[h] = make_float4(a, la2, (a < 0.f) ? 1.f : 0.f, (fabsf(a) < 1e-6f) ? 1.f : 0.f);
  } else {                                // lookback flags: zero 131072 u64
    flags[(bid - 4612) * 256 + tid] = 0ULL;
  }
}

// ---- fused: GEMM (z = x W^T + b) + chunk-parallel weighted-cumsum scan ----
// Grid: 2048 blocks; g = bid&127 (b = g>>3, chunk = g&7), strip = bid>>7.
// bid%8 == chunk -> each chunk's x-slice (16b x 128t = 2MB) + W is XCD-L2
// resident.  Lookback predecessors have strictly lower bid -> dispatch-safe.
// Block: 256 thr / 4 waves; tile 128x64; wave = (rw = w&1: 64 rows,
// cg = w>>1: 32 cols).  Depth-3 global_load_lds pipeline with counted vmcnt
// (never 0 mid-loop) + raw s_barrier: 2 tiles of HBM/L2 latency stay in
// flight across barriers.  k-major LDS tiles: every 16-lane ds_read_b128
// phase reads 256B contiguous -> bank-conflict-free.
__global__ __launch_bounds__(256, 4) void fused_rnn(
    const __bf16* __restrict__ xbt,  // [B][64][T][8] k-major
    const __bf16* __restrict__ wbT,  // [64][H][8]   k-major
    const float* __restrict__ bias,  // [H]
    const float4* __restrict__ meta, // [H]
    const float* __restrict__ h0g,   // [B, H]
    unsigned long long* __restrict__ flags, // [B][NSTRIP][NCH][NB] {flag|val}
    float* __restrict__ out) {       // [B*T, H]
  __shared__ __align__(16) __bf16 As[3][BKQ][TCH][8];  // 24 KB
  __shared__ __align__(16) __bf16 Bs[3][BKQ][NB][8];   // 12 KB
  __shared__ float chunkTot[2][NB];
  __shared__ float colCarry[NB];

  const int tid  = threadIdx.x;
  const int wave = tid >> 6;
  const int lane = tid & 63;
  const int q  = lane >> 4;      // 0..3
  const int c  = lane & 15;      // 0..15
  const int rw = wave & 1;       // row half: rows rw*64..+64
  const int cg = wave >> 1;      // col group: cols cg*32..+32

  const int bid   = blockIdx.x;
  const int g     = bid & 127;
  const int strip = bid >> 7;    // 0..15
  const int b     = g >> 3;
  const int chunk = g & 7;
  const int t0    = chunk * TCH;
  const int n0    = strip * NB;

  // per-lane column constants (2 cols per lane: cg*32 + j*16 + c)
  float bias_j[2], la2_j[2], h0_j[2];
  bool neg_j[2], zm_j[2];
#pragma unroll
  for (int j = 0; j < 2; ++j) {
    const int col = n0 + cg * 32 + j * 16 + c;
    bias_j[j] = bias[col];
    const float4 mt = meta[col];
    la2_j[j] = mt.y;
    neg_j[j] = mt.z != 0.f;
    zm_j[j]  = mt.w != 0.f;
    h0_j[j]  = h0g[(size_t)b * H_DIM + col];
  }

  // stage one BK=32 k-tile (A: 512 slots = 2 iters, B: 256 slots = 1 iter);
  // per-thread loads per tile L = 3 (the vmcnt counts below depend on this)
  auto stage = [&](int kt, int buf) {
    const int kq0 = kt * BKQ;
#pragma unroll
    for (int it = 0; it < 2; ++it) {
      const int s = it * 256 + tid;
      const int kq = s >> 7, row = s & 127;
      async_cp16(xbt + ((size_t)(b * 64 + kq0 + kq) * T_DIM + t0 + row) * 8,
                 &As[buf][kq][row][0]);
    }
    {
      const int kq = tid >> 6, col = tid & 63;
      async_cp16(wbT + ((size_t)(kq0 + kq) * H_DIM + n0 + col) * 8,
                 &Bs[buf][kq][col][0]);
    }
  };

  f32x4 acc[4][2];
#pragma unroll
  for (int i = 0; i < 4; ++i)
#pragma unroll
    for (int j = 0; j < 2; ++j) acc[i][j] = (f32x4){0.f, 0.f, 0.f, 0.f};

  // prologue: 3 tiles in flight
  stage(0, 0); stage(1, 1); stage(2, 2);

  int buf = 0;
  for (int kt = 0; kt < NKT; ++kt) {
    // wait for tile kt only; keep later tiles' loads in flight (3 loads/tile)
    if (kt < NKT - 2)       asm volatile("s_waitcnt vmcnt(6)" ::: "memory");
    else if (kt == NKT - 2) asm volatile("s_waitcnt vmcnt(3)" ::: "memory");
    else                    asm volatile("s_waitcnt vmcnt(0)" ::: "memory");
    __builtin_amdgcn_s_barrier();   // all threads' tile-kt loads done;
                                    // also: everyone finished reading buf (kt-3)
    bf16x8 af[4], bfr[2];
#pragma unroll
    for (int i = 0; i < 4; ++i)
      af[i] = *(const bf16x8*)(&As[buf][q][rw * 64 + i * 16 + c][0]);
#pragma unroll
    for (int j = 0; j < 2; ++j)
      bfr[j] = *(const bf16x8*)(&Bs[buf][q][cg * 32 + j * 16 + c][0]);
#pragma unroll
    for (int i = 0; i < 4; ++i)
#pragma unroll
      for (int j = 0; j < 2; ++j)
        acc[i][j] = __builtin_amdgcn_mfma_f32_16x16x32_bf16(af[i], bfr[j], acc[i][j], 0, 0, 0);
    __builtin_amdgcn_sched_barrier(0);  // no ds_read may sink past this point
    __builtin_amdgcn_s_barrier();       // all reads of buf done -> safe to restage
    if (kt < NKT - 3) stage(kt + 3, buf);
    buf = (buf == 2) ? 0 : buf + 1;
  }

  // ---- scan phase 1: per-wave weighted prefix over this wave's 64 rows ----
  // acc[i][j][r] = z for t = t0 + rw*64 + i*16 + q*4 + r, col = n0+cg*32+j*16+c
  f32x4 vloc[4][2];
  float icarry[2] = {0.f, 0.f};
#pragma unroll
  for (int i = 0; i < 4; ++i) {
#pragma unroll
    for (int j = 0; j < 2; ++j) {
      const float la2 = la2_j[j];
      f32x4 w;
#pragma unroll
      for (int r = 0; r < 4; ++r) {
        const int tp1 = t0 + rw * 64 + i * 16 + q * 4 + r + 1;
        const float z = acc[i][j][r] + bias_j[j];
        float inv = fminf(__builtin_amdgcn_exp2f(-la2 * (float)tp1), 1e12f);
        if (neg_j[j] && (tp1 & 1)) inv = 1e12f;   // matches ref's max(p,1e-12) for p<0
        w[r] = z * inv;
      }
      const float pr0 = w[0];
      const float pr1 = pr0 + w[1];
      const float pr2 = pr1 + w[2];
      const float pr3 = pr2 + w[3];
      const float x1 = __shfl_xor(pr3, 16, 64);   // q^1
      const float x2 = __shfl_xor(pr3, 32, 64);   // q^2
      const float x3 = __shfl_xor(pr3, 48, 64);   // q^3
      float sq = 0.f;
      if (q >= 2) sq += x2 + x3;
      if (q & 1) sq += x1;
      const float base = icarry[j] + sq;
      vloc[i][j] = (f32x4){base + pr0, base + pr1, base + pr2, base + pr3};
      icarry[j] += pr3 + x1 + x2 + x3;   // total over this i-group's 16 rows
    }
  }
  if (q == 0) {
#pragma unroll
    for (int j = 0; j < 2; ++j) chunkTot[rw][cg * 32 + j * 16 + c] = icarry[j];
  }
  __syncthreads();

  // ---- publish own chunk total, then decoupled lookback for the carry ----
  if (tid < NB) {
    const int col = tid;
    const size_t fb = ((size_t)b * NSTRIP + strip) * NCH * NB;
    const float tot = chunkTot[0][col] + chunkTot[1][col];
    atomicExch(&flags[fb + (size_t)chunk * NB + col],
               (1ULL << 32) | (unsigned long long)__float_as_uint(tot));
    float s = 0.f;
    for (int p = 0; p < chunk; ++p) {
      unsigned long long v = atomicAdd(&flags[fb + (size_t)p * NB + col], 0ULL);
      while (!(v >> 32)) {
        __builtin_amdgcn_s_sleep(4);
        v = atomicAdd(&flags[fb + (size_t)p * NB + col], 0ULL);
      }
      s += __uint_as_float((unsigned int)v);
    }
    colCarry[col] = s;
  }
  __syncthreads();

  // ---- phase 2: add carry, produce h, write out ----
  float cc[2];
#pragma unroll
  for (int j = 0; j < 2; ++j) {
    const int colL = cg * 32 + j * 16 + c;
    float s = colCarry[colL];
    if (rw) s += chunkTot[0][colL];
    cc[j] = s;
  }
#pragma unroll
  for (int i = 0; i < 4; ++i) {
#pragma unroll
    for (int j = 0; j < 2; ++j) {
      const float la2 = la2_j[j];
      const int col = n0 + cg * 32 + j * 16 + c;
#pragma unroll
      for (int r = 0; r < 4; ++r) {
        const int tl = t0 + rw * 64 + i * 16 + q * 4 + r;
        const int tp1 = tl + 1;
        float pv = __builtin_amdgcn_exp2f(la2 * (float)tp1);
        if (neg_j[j] && (tp1 & 1)) pv = -pv;
        const float v = cc[j] + vloc[i][j][r];
        const float hv = pv * v + pv * h0_j[j];
        const float zval = acc[i][j][r] + bias_j[j];
        out[(size_t)(b * T_DIM + tl) * H_DIM + col] = zm_j[j] ? zval : hv;
      }
    }
  }
}

extern "C" void kernel_launch(void* const* d_in, const int* in_sizes, int n_in,
                              void* d_out, int out_size, void* d_ws, size_t ws_size,
                              hipStream_t stream) {
  const float* x     = (const float*)d_in[0];  // [B,T,DK]
  const float* h0    = (const float*)d_in[1];  // [B,H]
  const float* raw_a = (const float*)d_in[2];  // [H]
  const float* W     = (const float*)d_in[3];  // [H,DK]
  const float* bias  = (const float*)d_in[4];  // [H]
  float* out = (float*)d_out;                  // [B,T,H]

  char* ws = (char*)d_ws;
  __bf16* xbt = (__bf16*)(ws);                               // 16777216 B
  __bf16* wbT = (__bf16*)(ws + 16777216);                    //  1048576 B
  float4* meta = (float4*)(ws + 16777216 + 1048576);         //    16384 B
  unsigned long long* flags =
      (unsigned long long*)(ws + 16777216 + 1048576 + 16384); // 1048576 B

  prep<<<5124, 256, 0, stream>>>(x, xbt, W, wbT, raw_a, meta, flags);
  fused_rnn<<<2048, 256, 0, stream>>>(xbt, wbT, bias, meta, h0, flags, out);
}

// Round 3
// 124.321 us; speedup vs baseline: 1.3861x; 1.0874x over previous
//
#include <hip/hip_runtime.h>
#include <cstdint>

// Problem dims (fixed by the reference)
#define B_DIM 16
#define T_DIM 1024
#define DK    512     // D_IN
#define H_DIM 1024

// Tiling
#define TCH    128                 // t-rows per block (chunk)
#define NCH    (T_DIM / TCH)       // 8 chunks per (b,strip)
#define NB     128                 // output cols per block
#define NSTRIP (H_DIM / NB)        // 8 strips
#define NKT    16                  // k-tiles of BK=32
#define BKQ    4                   // 16B k-chunks per k-tile

typedef __bf16 bf16x8 __attribute__((ext_vector_type(8)));
typedef __bf16 bf16x4 __attribute__((ext_vector_type(4)));
typedef float  f32x4  __attribute__((ext_vector_type(4)));

// ---- async global->LDS (16B per lane, wave-uniform LDS base + lane*16) ----
typedef __attribute__((address_space(1))) unsigned int* as1p;
typedef __attribute__((address_space(3))) unsigned int* as3p;

__device__ __forceinline__ void async_cp16(const void* g, void* l) {
  __builtin_amdgcn_global_load_lds((as1p)(uint64_t)g,
                                   (as3p)(uint32_t)(uint64_t)l, 16, 0, 0);
}

// ---- merged prep ----
// x: f32 [B][T][DK] -> bf16 k-major xbt[b][kq=0..63][t=0..1023][8]
// W: f32 [H][DK]    -> bf16 k-major wbT[kq][h][8]
// meta: {a, log2|a|, neg?, zero?} per h;  flags: zeroed lookback array.
// grid = 4096 (x) + 512 (W) + 4 (meta) + 512 (flags) = 5124 blocks x 256 thr
__global__ __launch_bounds__(256) void prep(const float* __restrict__ x,
                                            __bf16* __restrict__ xbt,
                                            const float* __restrict__ W,
                                            __bf16* __restrict__ wbT,
                                            const float* __restrict__ raw_a,
                                            float4* __restrict__ meta,
                                            unsigned long long* __restrict__ flags) {
  const int bid = blockIdx.x, tid = threadIdx.x;
  if (bid < 4096) {                       // x transpose + cvt, 8 elems/thread
    const int g = bid * 256 + tid;        // < 1048576
    const int b = g >> 16;
    const int r = g & 65535;
    // 4 lanes share a 128B x-row segment (coalesced reads);
    // 16 lanes of one kq write 256B contiguous in xbt (coalesced writes).
    const int kq = ((r >> 12) << 2) | (tid & 3);                // 0..63
    const int t  = (((r >> 6) & 63) << 4) | ((tid & 63) >> 2);  // 0..1023
    const float* src = x + ((size_t)(b * T_DIM + t) * DK + kq * 8);
    f32x4 v0 = ((const f32x4*)src)[0];
    f32x4 v1 = ((const f32x4*)src)[1];
    bf16x8 o;
    o[0] = (__bf16)v0.x; o[1] = (__bf16)v0.y; o[2] = (__bf16)v0.z; o[3] = (__bf16)v0.w;
    o[4] = (__bf16)v1.x; o[5] = (__bf16)v1.y; o[6] = (__bf16)v1.z; o[7] = (__bf16)v1.w;
    *(bf16x8*)(xbt + ((size_t)(b * 64 + kq) * T_DIM + t) * 8) = o;
  } else if (bid < 4608) {                // W -> wbT[kq][h][8]
    const int i = (bid - 4096) * 256 + tid;   // i < 131072
    const int h  = i >> 7;                // DK/4 = 128 x4-chunks per row
    const int k0 = (i & 127) * 4;
    f32x4 v = ((const f32x4*)W)[i];
    bf16x4 o;
    o.x = (__bf16)v.x; o.y = (__bf16)v.y; o.z = (__bf16)v.z; o.w = (__bf16)v.w;
    *(bf16x4*)(wbT + ((size_t)(k0 >> 3) * H_DIM + h) * 8 + (k0 & 7)) = o;
  } else if (bid < 4612) {                // meta
    const int h = (bid - 4608) * 256 + tid;
    const float a = tanhf(raw_a[h]);
    const float la2 = log2f(fabsf(a));
    meta[h] = make_float4(a, la2, (a < 0.f) ? 1.f : 0.f, (fabsf(a) < 1e-6f) ? 1.f : 0.f);
  } else {                                // lookback flags: zero 131072 u64
    flags[(bid - 4612) * 256 + tid] = 0ULL;
  }
}

// ---- fused: GEMM (z = x W^T + b) + chunk-parallel weighted-cumsum scan ----
// Grid: 1024 blocks; g = bid&127 (b = g>>3, chunk = g&7), strip = bid>>7.
// bid%8 == chunk -> all 8 strip-blocks of a (b,chunk) land on one XCD; its
// x-slice (16b x 128t = 2MB) + W (1MB) is XCD-L2-resident.  Lookback
// predecessors have strictly lower bid -> dispatch-order safe.
// Block: 256 thr / 4 waves; tile 128x128; wave = (rw = w&1: 64 rows,
// cg = w>>1: 64 cols) -> square 64x64 wave tiles (i=4 x j=4 16x16 frags):
// LDS-read bytes per FLOP 1.5x lower than 64x32.  Depth-3 global_load_lds
// pipeline, counted vmcnt (never 0 mid-loop), raw s_barrier.  k-major LDS
// tiles keep every 16-lane ds_read_b128 phase 256B-contiguous (0 conflicts).
__global__ __launch_bounds__(256, 3) void fused_rnn(
    const __bf16* __restrict__ xbt,  // [B][64][T][8] k-major
    const __bf16* __restrict__ wbT,  // [64][H][8]   k-major
    const float* __restrict__ bias,  // [H]
    const float4* __restrict__ meta, // [H]
    const float* __restrict__ h0g,   // [B, H]
    unsigned long long* __restrict__ flags, // [B][NSTRIP][NCH][NB] {flag|val}
    float* __restrict__ out) {       // [B*T, H]
  __shared__ __align__(16) __bf16 As[3][BKQ][TCH][8];  // 24 KB
  __shared__ __align__(16) __bf16 Bs[3][BKQ][NB][8];   // 24 KB
  __shared__ float chunkTot[2][NB];
  __shared__ float colCarry[NB];

  const int tid  = threadIdx.x;
  const int wave = tid >> 6;
  const int lane = tid & 63;
  const int q  = lane >> 4;      // 0..3
  const int c  = lane & 15;      // 0..15
  const int rw = wave & 1;       // row half: rows rw*64..+64
  const int cg = wave >> 1;      // col half: cols cg*64..+64

  const int bid   = blockIdx.x;
  const int g     = bid & 127;
  const int strip = bid >> 7;    // 0..7
  const int b     = g >> 3;
  const int chunk = g & 7;
  const int t0    = chunk * TCH;
  const int n0    = strip * NB;

  // per-lane column constants (4 cols per lane: cg*64 + j*16 + c)
  float bias_j[4], la2_j[4], a_j[4], ai_j[4], sgn_j[4], h0_j[4];
  bool zm_j[4];
#pragma unroll
  for (int j = 0; j < 4; ++j) {
    const int col = n0 + cg * 64 + j * 16 + c;
    bias_j[j] = bias[col];
    const float4 mt = meta[col];
    a_j[j]   = mt.x;
    la2_j[j] = mt.y;
    ai_j[j]  = 1.f / mt.x;              // signed 1/a (inf for a~0: handled)
    sgn_j[j] = (mt.z != 0.f) ? -1.f : 1.f;
    zm_j[j]  = mt.w != 0.f;
    h0_j[j]  = h0g[(size_t)b * H_DIM + col];
  }

  // stage one BK=32 k-tile (A: 512 slots, B: 512 slots -> 4 cp16/thread);
  // vmcnt counts below depend on 4 loads/thread/tile
  auto stage = [&](int kt, int buf) {
    const int kq0 = kt * BKQ;
#pragma unroll
    for (int it = 0; it < 2; ++it) {
      const int s = it * 256 + tid;
      const int kq = s >> 7, row = s & 127;
      async_cp16(xbt + ((size_t)(b * 64 + kq0 + kq) * T_DIM + t0 + row) * 8,
                 &As[buf][kq][row][0]);
    }
#pragma unroll
    for (int it = 0; it < 2; ++it) {
      const int s = it * 256 + tid;
      const int kq = s >> 7, col = s & 127;
      async_cp16(wbT + ((size_t)(kq0 + kq) * H_DIM + n0 + col) * 8,
                 &Bs[buf][kq][col][0]);
    }
  };

  // bias folded into the MFMA C-init (all 4 rows of a frag share the column)
  f32x4 acc[4][4];
#pragma unroll
  for (int i = 0; i < 4; ++i)
#pragma unroll
    for (int j = 0; j < 4; ++j)
      acc[i][j] = (f32x4){bias_j[j], bias_j[j], bias_j[j], bias_j[j]};

  // prologue: 3 tiles in flight
  stage(0, 0); stage(1, 1); stage(2, 2);

  int buf = 0;
  for (int kt = 0; kt < NKT; ++kt) {
    // wait for tile kt only; later tiles' loads stay in flight (4 loads/tile)
    if (kt < NKT - 2)       asm volatile("s_waitcnt vmcnt(8)" ::: "memory");
    else if (kt == NKT - 2) asm volatile("s_waitcnt vmcnt(4)" ::: "memory");
    else                    asm volatile("s_waitcnt vmcnt(0)" ::: "memory");
    __builtin_amdgcn_s_barrier();   // tile-kt loads visible to all waves;
                                    // everyone also done reading buf (kt-3)
    bf16x8 af[4], bfr[4];
#pragma unroll
    for (int i = 0; i < 4; ++i)
      af[i] = *(const bf16x8*)(&As[buf][q][rw * 64 + i * 16 + c][0]);
#pragma unroll
    for (int j = 0; j < 4; ++j)
      bfr[j] = *(const bf16x8*)(&Bs[buf][q][cg * 64 + j * 16 + c][0]);
#pragma unroll
    for (int i = 0; i < 4; ++i)
#pragma unroll
      for (int j = 0; j < 4; ++j)
        acc[i][j] = __builtin_amdgcn_mfma_f32_16x16x32_bf16(af[i], bfr[j], acc[i][j], 0, 0, 0);
    __builtin_amdgcn_sched_barrier(0);  // no ds_read may sink past this point
    __builtin_amdgcn_s_barrier();       // all reads of buf done -> restage ok
    if (kt < NKT - 3) stage(kt + 3, buf);
    buf = (buf == 2) ? 0 : buf + 1;
  }

  // ---- scan phase 1: per-wave weighted prefix over this wave's 64 rows ----
  // acc[i][j][r] = z (incl. bias) at t = t0+rw*64+i*16+q*4+r, col = n0+cg*64+j*16+c.
  // tp1 = t+1 is ODD at r=0 (all terms even +1), so the sign of a^(t+1) at r=0
  // is sgn (a<0 -> negative), and multiplying by signed a / 1/a alternates it.
  // inv = (u<0) ? 1e12 : min(u,1e12) reproduces ref's 1/max(p,1e-12) exactly.
  float base_[4][4];
  float icarry[4] = {0.f, 0.f, 0.f, 0.f};
#pragma unroll
  for (int i = 0; i < 4; ++i) {
    const int tp10 = t0 + rw * 64 + i * 16 + q * 4 + 1;
#pragma unroll
    for (int j = 0; j < 4; ++j) {
      float u = __builtin_amdgcn_exp2f(-la2_j[j] * (float)tp10) * sgn_j[j];
      f32x4 wv;
#pragma unroll
      for (int r = 0; r < 4; ++r) {
        const float uu = fminf(u, 1e12f);
        const float inv = (u < 0.f) ? 1e12f : uu;
        wv[r] = acc[i][j][r] * inv;
        u *= ai_j[j];
      }
      const float pr0 = wv[0];
      const float pr1 = pr0 + wv[1];
      const float pr2 = pr1 + wv[2];
      const float pr3 = pr2 + wv[3];
      const float x1 = __shfl_xor(pr3, 16, 64);   // q^1
      const float x2 = __shfl_xor(pr3, 32, 64);   // q^2
      const float x3 = __shfl_xor(pr3, 48, 64);   // q^3
      float sq = 0.f;
      if (q >= 2) sq += x2 + x3;
      if (q & 1) sq += x1;
      const float base = icarry[j] + sq;
      base_[i][j] = base;
      acc[i][j] = (f32x4){base + pr0, base + pr1, base + pr2, base + pr3};
      icarry[j] += pr3 + x1 + x2 + x3;   // total over this i-group's 16 rows
    }
  }
  if (q == 0) {
#pragma unroll
    for (int j = 0; j < 4; ++j) chunkTot[rw][cg * 64 + j * 16 + c] = icarry[j];
  }
  __syncthreads();

  // ---- publish own chunk total, then decoupled lookback for the carry ----
  if (tid < NB) {
    const int col = tid;
    const size_t fb = ((size_t)b * NSTRIP + strip) * NCH * NB;
    const float tot = chunkTot[0][col] + chunkTot[1][col];
    atomicExch(&flags[fb + (size_t)chunk * NB + col],
               (1ULL << 32) | (unsigned long long)__float_as_uint(tot));
    float s = 0.f;
    for (int p = 0; p < chunk; ++p) {
      unsigned long long v = atomicAdd(&flags[fb + (size_t)p * NB + col], 0ULL);
      while (!(v >> 32)) {
        __builtin_amdgcn_s_sleep(4);
        v = atomicAdd(&flags[fb + (size_t)p * NB + col], 0ULL);
      }
      s += __uint_as_float((unsigned int)v);
    }
    colCarry[col] = s;
  }
  __syncthreads();

  // ---- phase 2: add carry (+h0), produce h = p*(v+h0), write out ----
  float cc_[4];
#pragma unroll
  for (int j = 0; j < 4; ++j) {
    const int colL = cg * 64 + j * 16 + c;
    float s = colCarry[colL];
    if (rw) s += chunkTot[0][colL];
    cc_[j] = s + h0_j[j];
  }
#pragma unroll
  for (int i = 0; i < 4; ++i) {
    const int tp10 = t0 + rw * 64 + i * 16 + q * 4 + 1;
#pragma unroll
    for (int j = 0; j < 4; ++j) {
      float pv = __builtin_amdgcn_exp2f(la2_j[j] * (float)tp10) * sgn_j[j];
      const int col = n0 + cg * 64 + j * 16 + c;
#pragma unroll
      for (int r = 0; r < 4; ++r) {
        const int tl = t0 + rw * 64 + i * 16 + q * 4 + r;
        const float hv = pv * (acc[i][j][r] + cc_[j]);
        // zero-mask path: recover z = w*1e-12 (inv == 1e12 exactly when zm)
        const float wr = acc[i][j][r] - ((r == 0) ? base_[i][j] : acc[i][j][r - 1]);
        out[(size_t)(b * T_DIM + tl) * H_DIM + col] = zm_j[j] ? wr * 1e-12f : hv;
        pv *= a_j[j];
      }
    }
  }
}

extern "C" void kernel_launch(void* const* d_in, const int* in_sizes, int n_in,
                              void* d_out, int out_size, void* d_ws, size_t ws_size,
                              hipStream_t stream) {
  const float* x     = (const float*)d_in[0];  // [B,T,DK]
  const float* h0    = (const float*)d_in[1];  // [B,H]
  const float* raw_a = (const float*)d_in[2];  // [H]
  const float* W     = (const float*)d_in[3];  // [H,DK]
  const float* bias  = (const float*)d_in[4];  // [H]
  float* out = (float*)d_out;                  // [B,T,H]

  char* ws = (char*)d_ws;
  __bf16* xbt = (__bf16*)(ws);                               // 16777216 B
  __bf16* wbT = (__bf16*)(ws + 16777216);                    //  1048576 B
  float4* meta = (float4*)(ws + 16777216 + 1048576);         //    16384 B
  unsigned long long* flags =
      (unsigned long long*)(ws + 16777216 + 1048576 + 16384); // 1048576 B

  prep<<<5124, 256, 0, stream>>>(x, xbt, W, wbT, raw_a, meta, flags);
  fused_rnn<<<1024, 256, 0, stream>>>(xbt, wbT, bias, meta, h0, flags, out);
}